// Round 20
// baseline (211.798 us; speedup 1.0000x reference)
//
#include <hip/hip_runtime.h>
#include <math.h>

#define HIDDEN 4096
#define NEXP 64
#define TOPK 8
#define MARGIN 2.5e-4f
#define BK 64             // k-elements per chunk; 2 slices of 32
#define TPB 8
#define NCHUNK (HIDDEN / BK)   // 64

using short8   = __attribute__((ext_vector_type(8))) short;   // 8 bf16 fragment
using floatx4  = __attribute__((ext_vector_type(4))) float;   // MFMA acc
using uint4v   = __attribute__((ext_vector_type(4))) unsigned int;

// d_ws: [0,4) redo cnt | [64, 64+64K) redo list |
//       [128K, 640K) W'hi packed frags | [768K, 1280K) W'lo packed frags
#define WS_LIST_OFF  (64)
#define WS_WHP_OFF   (128 * 1024)
#define WS_WLP_OFF   (768 * 1024)
#define WS_NEED      (1280 * 1024)

__device__ __forceinline__ unsigned short bf16_rn(float x) {
    unsigned int u = __builtin_bit_cast(unsigned int, x);
    unsigned int r = u + 0x7FFFu + ((u >> 16) & 1u);
    return (unsigned short)(r >> 16);
}
__device__ __forceinline__ float bf16_to_f(unsigned short h) {
    unsigned int u = ((unsigned int)h) << 16;
    return __builtin_bit_cast(float, u);
}

// ---- pass 0 (r11-proven): W -> bf16 hi/lo packed frag order ---------------
// frag (c32, et), lane l, j: e = et*16+(l&15), k = c32*32+(l>>4)*8+j.
// packed ushort offset = ((c32*4 + et)*64 + l)*8 + j.
__global__ void wconv_kernel(const float* __restrict__ W,
                             unsigned short* __restrict__ Whp,
                             unsigned short* __restrict__ Wlp,
                             int* __restrict__ cnt) {
    if (blockIdx.x == 0 && threadIdx.x == 0) *cnt = 0;
    const int id  = blockIdx.x * 256 + threadIdx.x;
    const int c32 = id >> 8;
    const int et  = (id >> 6) & 3;
    const int l   = id & 63;
    const int e   = et * 16 + (l & 15);
    const int k0  = c32 * 32 + (l >> 4) * 8;
    const float4 a = *reinterpret_cast<const float4*>(W + (size_t)e * HIDDEN + k0);
    const float4 b = *reinterpret_cast<const float4*>(W + (size_t)e * HIDDEN + k0 + 4);
    const float xs[8] = {a.x, a.y, a.z, a.w, b.x, b.y, b.z, b.w};
    short8 hv, lv;
#pragma unroll
    for (int j = 0; j < 8; ++j) {
        unsigned short h = bf16_rn(xs[j]);
        hv[j] = (short)h;
        lv[j] = (short)bf16_rn(xs[j] - bf16_to_f(h));
    }
    const size_t off = ((size_t)(c32 * 4 + et) * 64 + l) * 8;
    *reinterpret_cast<short8*>(Whp + off) = hv;
    *reinterpret_cast<short8*>(Wlp + off) = lv;
}

// ---- pass 1: MFMA gate — TPB=8 / BK=64 high-occupancy ---------------------
// 256 thr = 4 waves; block = 8 tok x 64 exp; wave q = expert tile q.
// Grid 2048 = 8 blocks/CU; launch_bounds(256,8) caps VGPR at 64 ->
// 8 waves/SIMD (r19 was grid+VGPR-capped at 4/SIMD; occupancy is the lever).
// MFMA rows 8..15 are never staged (garbage, never read) — MFMA is ~6% util,
// wasting half the M rows is free.
// Staging: thread (krow=tid>>5 in 0..7, kk=tid&31) loads float2 (k=2kk),
// converts to hi/lo bf16-pair u32s, ds_write_b32 into frag layout:
// off = 64*(k>>5) + ((((k>>3)&3)<<4) | krow), byte = (off<<4 ^ swz) + (k&7)*2,
// swz = ((off>>4)&7)<<4 (both-sides swizzle, read side identical).
__global__ __launch_bounds__(256, 8)
void gate_mfma(const float* __restrict__ X,
               const unsigned short* __restrict__ Whp,
               const unsigned short* __restrict__ Wlp,
               float* __restrict__ out_w, float* __restrict__ out_i,
               int* __restrict__ redo_cnt, int* __restrict__ redo_list, int T) {
    __shared__ __align__(16) char smem[12288];   // 3 x (2K hi + 2K lo)
    const int tid  = threadIdx.x;
    const int lane = tid & 63;
    const int q    = tid >> 6;              // 0..3 = expert tile
    const int t0   = blockIdx.x * TPB;
    const int krow = tid >> 5;              // staged token row 0..7
    const int kk   = tid & 31;              // k-pair index; k0 = 2*kk

    const float* xsrc = X + (size_t)(t0 + krow) * HIDDEN + kk * 2;

    float2 gx;                              // in-flight X (2 floats)
#define GXLOAD(c) do {                                                            \
    gx = *reinterpret_cast<const float2*>(xsrc + (c) * BK);                       \
} while (0)

    // precomputed staging address (within-buffer byte offset)
    const int k0_   = kk * 2;
    const int soff  = 64 * (k0_ >> 5) + ((((k0_ >> 3) & 3) << 4) | krow);
    const int sbyte = ((soff << 4) ^ (((soff >> 4) & 7) << 4)) + (k0_ & 7) * 2;

#define CONVWRITE(buf) do {                                                       \
    char* base_ = smem + (buf) * 4096;                                            \
    unsigned int u0_ = __builtin_bit_cast(unsigned int, gx.x);                    \
    unsigned int u1_ = __builtin_bit_cast(unsigned int, gx.y);                    \
    unsigned int H_  = __builtin_amdgcn_perm(u1_, u0_, 0x07060302u);              \
    float d0_ = gx.x - __builtin_bit_cast(float, u0_ & 0xFFFF0000u);              \
    float d1_ = gx.y - __builtin_bit_cast(float, u1_ & 0xFFFF0000u);              \
    unsigned int L_ = __builtin_amdgcn_perm(__builtin_bit_cast(unsigned int, d1_),\
                                            __builtin_bit_cast(unsigned int, d0_),\
                                            0x07060302u);                         \
    *reinterpret_cast<unsigned int*>(base_ + sbyte) = H_;                         \
    *reinterpret_cast<unsigned int*>(base_ + 2048 + sbyte) = L_;                  \
} while (0)

    // packed W' base for et=q; chunk c, half h: c32 = 2c + h
    const unsigned short* whb = Whp + (size_t)q * 512 + (size_t)lane * 8;
    const unsigned short* wlb = Wlp + (size_t)q * 512 + (size_t)lane * 8;
#define LOADW(WH, WL, c, h) do {                                                  \
    WH = *reinterpret_cast<const short8*>(whb + (size_t)(2 * (c) + (h)) * 2048);  \
    WL = *reinterpret_cast<const short8*>(wlb + (size_t)(2 * (c) + (h)) * 2048);  \
} while (0)

    floatx4 accA = {0.f,0.f,0.f,0.f}, accB = {0.f,0.f,0.f,0.f};

    // compute one 32-k slice: A-frag at off = 64*h + lane (rows 8-15 garbage)
#define COMPUTE_HALF(buf, h, WH, WL) do {                                         \
    const char* xb_ = smem + (buf) * 4096;                                        \
    const int off_  = 64 * (h) + lane;                                            \
    const int byte_ = (off_ << 4) ^ (((off_ >> 4) & 7) << 4);                     \
    const short8 ah_ = *reinterpret_cast<const short8*>(xb_ + byte_);             \
    const short8 al_ = *reinterpret_cast<const short8*>(xb_ + 2048 + byte_);      \
    floatx4& A_ = (h) ? accB : accA;                                              \
    A_ = __builtin_amdgcn_mfma_f32_16x16x32_bf16(ah_, WH, A_, 0, 0, 0);           \
    A_ = __builtin_amdgcn_mfma_f32_16x16x32_bf16(ah_, WL, A_, 0, 0, 0);           \
    A_ = __builtin_amdgcn_mfma_f32_16x16x32_bf16(al_, WH, A_, 0, 0, 0);           \
} while (0)

    short8 whA, wlA, whB, wlB;

    // prologue: stage chunks 0 and 1, preload W(0, h0)
    GXLOAD(0); CONVWRITE(0);
    GXLOAD(1); CONVWRITE(1);
    LOADW(whA, wlA, 0, 0);
    __builtin_amdgcn_sched_barrier(0);
    asm volatile("s_waitcnt lgkmcnt(0)\n\ts_barrier" ::: "memory");
    __builtin_amdgcn_sched_barrier(0);

#pragma unroll 1
    for (int c = 0; c < NCHUNK; ++c) {
        if (c + 2 < NCHUNK) GXLOAD(c + 2);           // issue early (T14)
        LOADW(whB, wlB, c, 1);
        __builtin_amdgcn_sched_barrier(0);
        COMPUTE_HALF(c % 3, 0, whA, wlA);
        if (c + 1 < NCHUNK) LOADW(whA, wlA, c + 1, 0);
        __builtin_amdgcn_sched_barrier(0);
        COMPUTE_HALF(c % 3, 1, whB, wlB);
        if (c + 2 < NCHUNK) CONVWRITE((c + 2) % 3);  // write late, 2 ahead
        __builtin_amdgcn_sched_barrier(0);
        asm volatile("s_waitcnt lgkmcnt(0)\n\ts_barrier" ::: "memory");
        __builtin_amdgcn_sched_barrier(0);
    }
    floatx4 acc;
#pragma unroll
    for (int r = 0; r < 4; ++r) acc[r] = accA[r] + accB[r];

    __syncthreads();
    // D layout (verified r4-r19): col = lane&15 (expert), row = (lane>>4)*4+r
    float* accs = reinterpret_cast<float*>(smem);   // [16][68] overlay (rows 8-15 garbage)
    const int drow = (lane >> 4) * 4;
    const int dcol = q * 16 + (lane & 15);
#pragma unroll
    for (int r = 0; r < 4; ++r) accs[(drow + r) * 68 + dcol] = acc[r];
    __syncthreads();

    // epilogue (proven): wave q handles rows 2q..2q+1; lane = expert
#pragma unroll 1
    for (int m = 0; m < 2; ++m) {
        const int row = q * 2 + m;
        const int t = t0 + row;
        float lg = accs[row * 68 + lane];
        float v = 30.0f * tanhf(lg * (1.0f / 30.0f));
        float vcur = v, vmax0 = 0.f, my_e = 0.f, sum = 0.f, prev = 0.f;
        int   my_i = 0;
        bool  ambig = false;
#pragma unroll 1
        for (int k = 0; k < TOPK + 1; ++k) {   // ranks 1..9 with margin check
            float bv = vcur;
            int   bi = lane;
#pragma unroll
            for (int s = 32; s >= 1; s >>= 1) {
                float ov = __shfl_xor(bv, s);
                int   oi = __shfl_xor(bi, s);
                if (ov > bv || (ov == bv && oi < bi)) { bv = ov; bi = oi; }
            }
            if (k == 0) vmax0 = bv;
            else        ambig |= (prev - bv < MARGIN);
            prev = bv;
            if (k < TOPK) {
                float e = __expf(bv - vmax0);
                sum += e;
                if (lane == k) { my_e = e; my_i = bi; }
                if (lane == bi) vcur = -INFINITY;
            }
        }
        if (!ambig) {
            if (lane < TOPK) {
                out_w[(size_t)t * TOPK + lane] = my_e / sum;
                out_i[(size_t)t * TOPK + lane] = (float)my_i;
            }
        } else if (lane == 0) {
            redo_list[atomicAdd(redo_cnt, 1)] = t;
        }
    }
#undef GXLOAD
#undef CONVWRITE
#undef LOADW
#undef COMPUTE_HALF
}

// ---- pass 2: exact f64 redo (proven, unchanged) ---------------------------
__global__ __launch_bounds__(256, 2)
void gate_redo(const float* __restrict__ X, const float* __restrict__ W,
               float* __restrict__ out,
               const int* __restrict__ redo_cnt, const int* __restrict__ redo_list,
               int T) {
    __shared__ double lgs[64];
    const int lane = threadIdx.x & 63;
    const int q    = threadIdx.x >> 6;
    const int n    = *redo_cnt;
    float* out_w = out;
    float* out_i = out + (size_t)T * TOPK;

    for (int i = blockIdx.x; i < n; i += gridDim.x) {
        const int t = redo_list[i];
        const float* xr = X + (size_t)t * HIDDEN;
#pragma unroll 1
        for (int j = 0; j < 16; ++j) {
            const int e = q * 16 + j;
            const float* wr = W + (size_t)e * HIDDEN;
            double s = 0.0;
#pragma unroll 2
            for (int k = lane * 4; k < HIDDEN; k += 256) {
                float4 wv = *reinterpret_cast<const float4*>(wr + k);
                float4 xv = *reinterpret_cast<const float4*>(xr + k);
                s = fma((double)xv.x, (double)wv.x, s);
                s = fma((double)xv.y, (double)wv.y, s);
                s = fma((double)xv.z, (double)wv.z, s);
                s = fma((double)xv.w, (double)wv.w, s);
            }
#pragma unroll
            for (int sft = 32; sft >= 1; sft >>= 1) s += __shfl_xor(s, sft);
            if (lane == 0) lgs[e] = s;
        }
        __syncthreads();
        if (q == 0) {
            double vv = 30.0 * tanh(lgs[lane] * (1.0 / 30.0));
            double dmax0 = 0.0, dmy_e = 0.0, dsum = 0.0;
            int    dmy_i = 0;
#pragma unroll 1
            for (int k = 0; k < TOPK; ++k) {
                double bv = vv;
                int    bi = lane;
#pragma unroll
                for (int s = 32; s >= 1; s >>= 1) {
                    double ov = __shfl_xor(bv, s);
                    int    oi = __shfl_xor(bi, s);
                    if (ov > bv || (ov == bv && oi < bi)) { bv = ov; bi = oi; }
                }
                if (k == 0) dmax0 = bv;
                double e = exp(bv - dmax0);
                dsum += e;
                if (lane == k) { dmy_e = e; dmy_i = bi; }
                if (lane == bi) vv = -HUGE_VAL;
            }
            if (lane < TOPK) {
                out_w[(size_t)t * TOPK + lane] = (float)(dmy_e / dsum);
                out_i[(size_t)t * TOPK + lane] = (float)dmy_i;
            }
        }
        __syncthreads();
    }
}

// ---- fallback (round-3 proven) --------------------------------------------
#define F_HC 64
#define F_LDS_STRIDE 68
#define F_TPW 4
#define F_TPB 16

__global__ __launch_bounds__(256, 4)
void moe_gate_fallback(const float* __restrict__ X, const float* __restrict__ W,
                       float* __restrict__ out, int T) {
    __shared__ float wlds[NEXP * F_LDS_STRIDE];
    const int tid  = threadIdx.x;
    const int lane = tid & 63;
    const int wid  = tid >> 6;
    const int t0   = blockIdx.x * F_TPB + wid * F_TPW;
    double accd[F_TPW];
#pragma unroll
    for (int m = 0; m < F_TPW; ++m) accd[m] = 0.0;
    for (int hb = 0; hb < HIDDEN; hb += F_HC) {
        __syncthreads();
#pragma unroll
        for (int k = 0; k < 4; ++k) {
            int f = tid + k * 256, e = f >> 4, c4 = f & 15;
            const float4 wv = *reinterpret_cast<const float4*>(W + e * HIDDEN + hb + c4 * 4);
            *reinterpret_cast<float4*>(&wlds[e * F_LDS_STRIDE + c4 * 4]) = wv;
        }
        __syncthreads();
        float accf[F_TPW];
#pragma unroll
        for (int m = 0; m < F_TPW; ++m) accf[m] = 0.f;
#pragma unroll 4
        for (int h4 = 0; h4 < F_HC / 4; ++h4) {
            const float4 wv = *reinterpret_cast<const float4*>(&wlds[lane * F_LDS_STRIDE + h4 * 4]);
#pragma unroll
            for (int m = 0; m < F_TPW; ++m) {
                const float4 xv = *reinterpret_cast<const float4*>(
                    X + (size_t)(t0 + m) * HIDDEN + hb + h4 * 4);
                accf[m] = fmaf(xv.x, wv.x, accf[m]);
                accf[m] = fmaf(xv.y, wv.y, accf[m]);
                accf[m] = fmaf(xv.z, wv.z, accf[m]);
                accf[m] = fmaf(xv.w, wv.w, accf[m]);
            }
        }
#pragma unroll
        for (int m = 0; m < F_TPW; ++m) accd[m] += (double)accf[m];
    }
    float* out_w = out;
    float* out_i = out + (size_t)T * TOPK;
#pragma unroll 1
    for (int m = 0; m < F_TPW; ++m) {
        const int t = t0 + m;
        double vv = 30.0 * tanh(accd[m] * (1.0 / 30.0));
        double dmax0 = 0.0, dmy_e = 0.0, dsum = 0.0;
        int dmy_i = 0;
#pragma unroll 1
        for (int k = 0; k < TOPK; ++k) {
            double bv = vv; int bi = lane;
#pragma unroll
            for (int s = 32; s >= 1; s >>= 1) {
                double ov = __shfl_xor(bv, s);
                int    oi = __shfl_xor(bi, s);
                if (ov > bv || (ov == bv && oi < bi)) { bv = ov; bi = oi; }
            }
            if (k == 0) dmax0 = bv;
            double e = exp(bv - dmax0);
            dsum += e;
            if (lane == k) { dmy_e = e; dmy_i = bi; }
            if (lane == bi) vv = -HUGE_VAL;
        }
        if (lane < TOPK) {
            out_w[(size_t)t * TOPK + lane] = (float)(dmy_e / dsum);
            out_i[(size_t)t * TOPK + lane] = (float)dmy_i;
        }
    }
}

extern "C" void kernel_launch(void* const* d_in, const int* in_sizes, int n_in,
                              void* d_out, int out_size, void* d_ws, size_t ws_size,
                              hipStream_t stream) {
    const float* X = (const float*)d_in[0];
    const float* W = (const float*)d_in[1];
    float* out = (float*)d_out;
    const int T = in_sizes[0] / HIDDEN;

    if (ws_size < WS_NEED) {
        hipLaunchKernelGGL(moe_gate_fallback, dim3(T / F_TPB), dim3(256), 0, stream, X, W, out, T);
        return;
    }
    char* ws = (char*)d_ws;
    int* cnt  = (int*)ws;
    int* list = (int*)(ws + WS_LIST_OFF);
    unsigned short* Whp = (unsigned short*)(ws + WS_WHP_OFF);
    unsigned short* Wlp = (unsigned short*)(ws + WS_WLP_OFF);

    hipLaunchKernelGGL(wconv_kernel, dim3(128), dim3(256), 0, stream, W, Whp, Wlp, cnt);
    hipLaunchKernelGGL(gate_mfma, dim3(T / TPB), dim3(256), 0, stream,
                       X, Whp, Wlp, out, out + (size_t)T * TOPK, cnt, list, T);
    hipLaunchKernelGGL(gate_redo, dim3(256), dim3(256), 0, stream,
                       X, W, out, cnt, list, T);
}

// Round 21
// 197.456 us; speedup vs baseline: 1.0726x; 1.0726x over previous
//
#include <hip/hip_runtime.h>
#include <math.h>

#define HIDDEN 4096
#define NEXP 64
#define TOPK 8
#define MARGIN 2.5e-4f
#define BK 128            // k-elements per chunk; 4 slices of 32
#define TPB 8
#define NCHUNK (HIDDEN / BK)   // 32

using short8   = __attribute__((ext_vector_type(8))) short;   // 8 bf16 fragment
using floatx4  = __attribute__((ext_vector_type(4))) float;   // MFMA acc
using uint2v   = __attribute__((ext_vector_type(2))) unsigned int;
using uint4v   = __attribute__((ext_vector_type(4))) unsigned int;

// d_ws: [0,4) redo cnt | [64, 64+64K) redo list |
//       [128K, 640K) W'hi packed frags | [768K, 1280K) W'lo packed frags
#define WS_LIST_OFF  (64)
#define WS_WHP_OFF   (128 * 1024)
#define WS_WLP_OFF   (768 * 1024)
#define WS_NEED      (1280 * 1024)

__device__ __forceinline__ unsigned short bf16_rn(float x) {
    unsigned int u = __builtin_bit_cast(unsigned int, x);
    unsigned int r = u + 0x7FFFu + ((u >> 16) & 1u);
    return (unsigned short)(r >> 16);
}
__device__ __forceinline__ float bf16_to_f(unsigned short h) {
    unsigned int u = ((unsigned int)h) << 16;
    return __builtin_bit_cast(float, u);
}

// ---- pass 0 (r11-proven): W -> bf16 hi/lo packed frag order ---------------
// frag (c32, et), lane l, j: e = et*16+(l&15), k = c32*32+(l>>4)*8+j.
// packed ushort offset = ((c32*4 + et)*64 + l)*8 + j.
__global__ void wconv_kernel(const float* __restrict__ W,
                             unsigned short* __restrict__ Whp,
                             unsigned short* __restrict__ Wlp,
                             int* __restrict__ cnt) {
    if (blockIdx.x == 0 && threadIdx.x == 0) *cnt = 0;
    const int id  = blockIdx.x * 256 + threadIdx.x;
    const int c32 = id >> 8;
    const int et  = (id >> 6) & 3;
    const int l   = id & 63;
    const int e   = et * 16 + (l & 15);
    const int k0  = c32 * 32 + (l >> 4) * 8;
    const float4 a = *reinterpret_cast<const float4*>(W + (size_t)e * HIDDEN + k0);
    const float4 b = *reinterpret_cast<const float4*>(W + (size_t)e * HIDDEN + k0 + 4);
    const float xs[8] = {a.x, a.y, a.z, a.w, b.x, b.y, b.z, b.w};
    short8 hv, lv;
#pragma unroll
    for (int j = 0; j < 8; ++j) {
        unsigned short h = bf16_rn(xs[j]);
        hv[j] = (short)h;
        lv[j] = (short)bf16_rn(xs[j] - bf16_to_f(h));
    }
    const size_t off = ((size_t)(c32 * 4 + et) * 64 + l) * 8;
    *reinterpret_cast<short8*>(Whp + off) = hv;
    *reinterpret_cast<short8*>(Wlp + off) = lv;
}

// ---- pass 1: MFMA gate — TPB=8 / BK=128 (6 blocks/CU, r19 chunk count) ----
// 256 thr = 4 waves; block = 8 tok x 64 exp; wave q = expert tile q.
// Grid 2048; LDS 3 x 8 KB = 24 KB -> 6 blocks/CU (r19 grid-capped at 4).
// Chunk structure (4 slices, barrier pattern, W' indexing) identical to r19.
// MFMA rows 8..15 garbage (never staged/read — free at ~10% MfmaUtil, r20).
// Staging: thread (krow=tid>>5, kk=tid&31) loads float4 (k0=4kk), converts
// to hi/lo bf16-pair u32 pairs, 8B ds_writes into frag layout:
// off = 64*(k0>>5) + ((((k0>>3)&3)<<4) | krow),
// byte = (off<<4 ^ ((off>>4&7)<<4)) + (k0&7)*2  (both-sides swizzle).
__global__ __launch_bounds__(256, 6)
void gate_mfma(const float* __restrict__ X,
               const unsigned short* __restrict__ Whp,
               const unsigned short* __restrict__ Wlp,
               float* __restrict__ out_w, float* __restrict__ out_i,
               int* __restrict__ redo_cnt, int* __restrict__ redo_list, int T) {
    __shared__ __align__(16) char smem[24576];   // 3 x (4K hi + 4K lo)
    const int tid  = threadIdx.x;
    const int lane = tid & 63;
    const int q    = tid >> 6;              // 0..3 = expert tile
    const int t0   = blockIdx.x * TPB;
    const int krow = tid >> 5;              // staged token row 0..7
    const int kk   = tid & 31;              // k-quad index; k0 = 4*kk

    const float* xsrc = X + (size_t)(t0 + krow) * HIDDEN + kk * 4;

    float4 gx;                              // in-flight X (4 floats)
#define GXLOAD(c) do {                                                            \
    gx = *reinterpret_cast<const float4*>(xsrc + (c) * BK);                       \
} while (0)

    // precomputed staging address (within-buffer byte offset)
    const int k0_   = kk * 4;
    const int soff  = 64 * (k0_ >> 5) + ((((k0_ >> 3) & 3) << 4) | krow);
    const int sbyte = ((soff << 4) ^ (((soff >> 4) & 7) << 4)) + (k0_ & 7) * 2;

#define CONVWRITE(buf) do {                                                       \
    char* base_ = smem + (buf) * 8192;                                            \
    unsigned int u0_ = __builtin_bit_cast(unsigned int, gx.x);                    \
    unsigned int u1_ = __builtin_bit_cast(unsigned int, gx.y);                    \
    unsigned int u2_ = __builtin_bit_cast(unsigned int, gx.z);                    \
    unsigned int u3_ = __builtin_bit_cast(unsigned int, gx.w);                    \
    unsigned int H0_ = __builtin_amdgcn_perm(u1_, u0_, 0x07060302u);              \
    unsigned int H1_ = __builtin_amdgcn_perm(u3_, u2_, 0x07060302u);              \
    float d0_ = gx.x - __builtin_bit_cast(float, u0_ & 0xFFFF0000u);              \
    float d1_ = gx.y - __builtin_bit_cast(float, u1_ & 0xFFFF0000u);              \
    float d2_ = gx.z - __builtin_bit_cast(float, u2_ & 0xFFFF0000u);              \
    float d3_ = gx.w - __builtin_bit_cast(float, u3_ & 0xFFFF0000u);              \
    unsigned int L0_ = __builtin_amdgcn_perm(__builtin_bit_cast(unsigned int, d1_),\
                                             __builtin_bit_cast(unsigned int, d0_),\
                                             0x07060302u);                        \
    unsigned int L1_ = __builtin_amdgcn_perm(__builtin_bit_cast(unsigned int, d3_),\
                                             __builtin_bit_cast(unsigned int, d2_),\
                                             0x07060302u);                        \
    uint2v hv_ = {H0_, H1_};                                                      \
    uint2v lv_ = {L0_, L1_};                                                      \
    *reinterpret_cast<uint2v*>(base_ + sbyte) = hv_;                              \
    *reinterpret_cast<uint2v*>(base_ + 4096 + sbyte) = lv_;                       \
} while (0)

    // packed W' base for et=q; chunk c, half h, sub s_: c32 = 4c + 2h + s_
    const unsigned short* whb = Whp + (size_t)q * 512 + (size_t)lane * 8;
    const unsigned short* wlb = Wlp + (size_t)q * 512 + (size_t)lane * 8;
#define LOADW(WH, WL, c, h) do {                                                  \
    _Pragma("unroll")                                                             \
    for (int s_ = 0; s_ < 2; ++s_) {                                              \
        WH[s_] = *reinterpret_cast<const short8*>(                                \
            whb + (size_t)(4 * (c) + 2 * (h) + s_) * 2048);                       \
        WL[s_] = *reinterpret_cast<const short8*>(                                \
            wlb + (size_t)(4 * (c) + 2 * (h) + s_) * 2048);                       \
    }                                                                             \
} while (0)

    floatx4 accA = {0.f,0.f,0.f,0.f}, accB = {0.f,0.f,0.f,0.f};

    // pure-frag compute: slice sl = 2h + s_; A-frag at off = 64*sl + lane
#define COMPUTE_HALF(buf, h, WH, WL) do {                                         \
    const char* xb_ = smem + (buf) * 8192;                                        \
    _Pragma("unroll")                                                             \
    for (int s_ = 0; s_ < 2; ++s_) {                                              \
        const int off_  = 64 * (2 * (h) + s_) + lane;                             \
        const int byte_ = (off_ << 4) ^ (((off_ >> 4) & 7) << 4);                 \
        const short8 ah_ = *reinterpret_cast<const short8*>(xb_ + byte_);         \
        const short8 al_ = *reinterpret_cast<const short8*>(xb_ + 4096 + byte_);  \
        floatx4& A_ = (s_ & 1) ? accB : accA;                                     \
        A_ = __builtin_amdgcn_mfma_f32_16x16x32_bf16(ah_, WH[s_], A_, 0, 0, 0);   \
        A_ = __builtin_amdgcn_mfma_f32_16x16x32_bf16(ah_, WL[s_], A_, 0, 0, 0);   \
        A_ = __builtin_amdgcn_mfma_f32_16x16x32_bf16(al_, WH[s_], A_, 0, 0, 0);   \
    }                                                                             \
} while (0)

    short8 whA[2], wlA[2], whB[2], wlB[2];

    // prologue: stage chunks 0 and 1, preload W(0, h0)
    GXLOAD(0); CONVWRITE(0);
    GXLOAD(1); CONVWRITE(1);
    LOADW(whA, wlA, 0, 0);
    __builtin_amdgcn_sched_barrier(0);
    asm volatile("s_waitcnt lgkmcnt(0)\n\ts_barrier" ::: "memory");
    __builtin_amdgcn_sched_barrier(0);

#pragma unroll 1
    for (int c = 0; c < NCHUNK; ++c) {
        if (c + 2 < NCHUNK) GXLOAD(c + 2);           // issue early (T14)
        LOADW(whB, wlB, c, 1);
        __builtin_amdgcn_sched_barrier(0);
        COMPUTE_HALF(c % 3, 0, whA, wlA);
        if (c + 1 < NCHUNK) LOADW(whA, wlA, c + 1, 0);
        __builtin_amdgcn_sched_barrier(0);
        COMPUTE_HALF(c % 3, 1, whB, wlB);
        if (c + 2 < NCHUNK) CONVWRITE((c + 2) % 3);  // write late, 2 ahead
        __builtin_amdgcn_sched_barrier(0);
        asm volatile("s_waitcnt lgkmcnt(0)\n\ts_barrier" ::: "memory");
        __builtin_amdgcn_sched_barrier(0);
    }
    floatx4 acc;
#pragma unroll
    for (int r = 0; r < 4; ++r) acc[r] = accA[r] + accB[r];

    __syncthreads();
    // D layout (verified r4-r20): col = lane&15 (expert), row = (lane>>4)*4+r
    float* accs = reinterpret_cast<float*>(smem);   // [16][68] overlay (rows 8-15 garbage)
    const int drow = (lane >> 4) * 4;
    const int dcol = q * 16 + (lane & 15);
#pragma unroll
    for (int r = 0; r < 4; ++r) accs[(drow + r) * 68 + dcol] = acc[r];
    __syncthreads();

    // epilogue (proven): wave q handles rows 2q..2q+1; lane = expert
#pragma unroll 1
    for (int m = 0; m < 2; ++m) {
        const int row = q * 2 + m;
        const int t = t0 + row;
        float lg = accs[row * 68 + lane];
        float v = 30.0f * tanhf(lg * (1.0f / 30.0f));
        float vcur = v, vmax0 = 0.f, my_e = 0.f, sum = 0.f, prev = 0.f;
        int   my_i = 0;
        bool  ambig = false;
#pragma unroll 1
        for (int k = 0; k < TOPK + 1; ++k) {   // ranks 1..9 with margin check
            float bv = vcur;
            int   bi = lane;
#pragma unroll
            for (int s = 32; s >= 1; s >>= 1) {
                float ov = __shfl_xor(bv, s);
                int   oi = __shfl_xor(bi, s);
                if (ov > bv || (ov == bv && oi < bi)) { bv = ov; bi = oi; }
            }
            if (k == 0) vmax0 = bv;
            else        ambig |= (prev - bv < MARGIN);
            prev = bv;
            if (k < TOPK) {
                float e = __expf(bv - vmax0);
                sum += e;
                if (lane == k) { my_e = e; my_i = bi; }
                if (lane == bi) vcur = -INFINITY;
            }
        }
        if (!ambig) {
            if (lane < TOPK) {
                out_w[(size_t)t * TOPK + lane] = my_e / sum;
                out_i[(size_t)t * TOPK + lane] = (float)my_i;
            }
        } else if (lane == 0) {
            redo_list[atomicAdd(redo_cnt, 1)] = t;
        }
    }
#undef GXLOAD
#undef CONVWRITE
#undef LOADW
#undef COMPUTE_HALF
}

// ---- pass 2: exact f64 redo (proven, unchanged) ---------------------------
__global__ __launch_bounds__(256, 2)
void gate_redo(const float* __restrict__ X, const float* __restrict__ W,
               float* __restrict__ out,
               const int* __restrict__ redo_cnt, const int* __restrict__ redo_list,
               int T) {
    __shared__ double lgs[64];
    const int lane = threadIdx.x & 63;
    const int q    = threadIdx.x >> 6;
    const int n    = *redo_cnt;
    float* out_w = out;
    float* out_i = out + (size_t)T * TOPK;

    for (int i = blockIdx.x; i < n; i += gridDim.x) {
        const int t = redo_list[i];
        const float* xr = X + (size_t)t * HIDDEN;
#pragma unroll 1
        for (int j = 0; j < 16; ++j) {
            const int e = q * 16 + j;
            const float* wr = W + (size_t)e * HIDDEN;
            double s = 0.0;
#pragma unroll 2
            for (int k = lane * 4; k < HIDDEN; k += 256) {
                float4 wv = *reinterpret_cast<const float4*>(wr + k);
                float4 xv = *reinterpret_cast<const float4*>(xr + k);
                s = fma((double)xv.x, (double)wv.x, s);
                s = fma((double)xv.y, (double)wv.y, s);
                s = fma((double)xv.z, (double)wv.z, s);
                s = fma((double)xv.w, (double)wv.w, s);
            }
#pragma unroll
            for (int sft = 32; sft >= 1; sft >>= 1) s += __shfl_xor(s, sft);
            if (lane == 0) lgs[e] = s;
        }
        __syncthreads();
        if (q == 0) {
            double vv = 30.0 * tanh(lgs[lane] * (1.0 / 30.0));
            double dmax0 = 0.0, dmy_e = 0.0, dsum = 0.0;
            int    dmy_i = 0;
#pragma unroll 1
            for (int k = 0; k < TOPK; ++k) {
                double bv = vv;
                int    bi = lane;
#pragma unroll
                for (int s = 32; s >= 1; s >>= 1) {
                    double ov = __shfl_xor(bv, s);
                    int    oi = __shfl_xor(bi, s);
                    if (ov > bv || (ov == bv && oi < bi)) { bv = ov; bi = oi; }
                }
                if (k == 0) dmax0 = bv;
                double e = exp(bv - dmax0);
                dsum += e;
                if (lane == k) { dmy_e = e; dmy_i = bi; }
                if (lane == bi) vv = -HUGE_VAL;
            }
            if (lane < TOPK) {
                out_w[(size_t)t * TOPK + lane] = (float)(dmy_e / dsum);
                out_i[(size_t)t * TOPK + lane] = (float)dmy_i;
            }
        }
        __syncthreads();
    }
}

// ---- fallback (round-3 proven) --------------------------------------------
#define F_HC 64
#define F_LDS_STRIDE 68
#define F_TPW 4
#define F_TPB 16

__global__ __launch_bounds__(256, 4)
void moe_gate_fallback(const float* __restrict__ X, const float* __restrict__ W,
                       float* __restrict__ out, int T) {
    __shared__ float wlds[NEXP * F_LDS_STRIDE];
    const int tid  = threadIdx.x;
    const int lane = tid & 63;
    const int wid  = tid >> 6;
    const int t0   = blockIdx.x * F_TPB + wid * F_TPW;
    double accd[F_TPW];
#pragma unroll
    for (int m = 0; m < F_TPW; ++m) accd[m] = 0.0;
    for (int hb = 0; hb < HIDDEN; hb += F_HC) {
        __syncthreads();
#pragma unroll
        for (int k = 0; k < 4; ++k) {
            int f = tid + k * 256, e = f >> 4, c4 = f & 15;
            const float4 wv = *reinterpret_cast<const float4*>(W + e * HIDDEN + hb + c4 * 4);
            *reinterpret_cast<float4*>(&wlds[e * F_LDS_STRIDE + c4 * 4]) = wv;
        }
        __syncthreads();
        float accf[F_TPW];
#pragma unroll
        for (int m = 0; m < F_TPW; ++m) accf[m] = 0.f;
#pragma unroll 4
        for (int h4 = 0; h4 < F_HC / 4; ++h4) {
            const float4 wv = *reinterpret_cast<const float4*>(&wlds[lane * F_LDS_STRIDE + h4 * 4]);
#pragma unroll
            for (int m = 0; m < F_TPW; ++m) {
                const float4 xv = *reinterpret_cast<const float4*>(
                    X + (size_t)(t0 + m) * HIDDEN + hb + h4 * 4);
                accf[m] = fmaf(xv.x, wv.x, accf[m]);
                accf[m] = fmaf(xv.y, wv.y, accf[m]);
                accf[m] = fmaf(xv.z, wv.z, accf[m]);
                accf[m] = fmaf(xv.w, wv.w, accf[m]);
            }
        }
#pragma unroll
        for (int m = 0; m < F_TPW; ++m) accd[m] += (double)accf[m];
    }
    float* out_w = out;
    float* out_i = out + (size_t)T * TOPK;
#pragma unroll 1
    for (int m = 0; m < F_TPW; ++m) {
        const int t = t0 + m;
        double vv = 30.0 * tanh(accd[m] * (1.0 / 30.0));
        double dmax0 = 0.0, dmy_e = 0.0, dsum = 0.0;
        int dmy_i = 0;
#pragma unroll 1
        for (int k = 0; k < TOPK; ++k) {
            double bv = vv; int bi = lane;
#pragma unroll
            for (int s = 32; s >= 1; s >>= 1) {
                double ov = __shfl_xor(bv, s);
                int    oi = __shfl_xor(bi, s);
                if (ov > bv || (ov == bv && oi < bi)) { bv = ov; bi = oi; }
            }
            if (k == 0) dmax0 = bv;
            double e = exp(bv - dmax0);
            dsum += e;
            if (lane == k) { dmy_e = e; dmy_i = bi; }
            if (lane == bi) vv = -HUGE_VAL;
        }
        if (lane < TOPK) {
            out_w[(size_t)t * TOPK + lane] = (float)(dmy_e / dsum);
            out_i[(size_t)t * TOPK + lane] = (float)dmy_i;
        }
    }
}

extern "C" void kernel_launch(void* const* d_in, const int* in_sizes, int n_in,
                              void* d_out, int out_size, void* d_ws, size_t ws_size,
                              hipStream_t stream) {
    const float* X = (const float*)d_in[0];
    const float* W = (const float*)d_in[1];
    float* out = (float*)d_out;
    const int T = in_sizes[0] / HIDDEN;

    if (ws_size < WS_NEED) {
        hipLaunchKernelGGL(moe_gate_fallback, dim3(T / F_TPB), dim3(256), 0, stream, X, W, out, T);
        return;
    }
    char* ws = (char*)d_ws;
    int* cnt  = (int*)ws;
    int* list = (int*)(ws + WS_LIST_OFF);
    unsigned short* Whp = (unsigned short*)(ws + WS_WHP_OFF);
    unsigned short* Wlp = (unsigned short*)(ws + WS_WLP_OFF);

    hipLaunchKernelGGL(wconv_kernel, dim3(128), dim3(256), 0, stream, W, Whp, Wlp, cnt);
    hipLaunchKernelGGL(gate_mfma, dim3(T / TPB), dim3(256), 0, stream,
                       X, Whp, Wlp, out, out + (size_t)T * TOPK, cnt, list, T);
    hipLaunchKernelGGL(gate_redo, dim3(256), dim3(256), 0, stream,
                       X, W, out, cnt, list, T);
}

// Round 22
// 149.750 us; speedup vs baseline: 1.4143x; 1.3186x over previous
//
#include <hip/hip_runtime.h>
#include <math.h>

#define HIDDEN 4096
#define NEXP 64
#define TOPK 8
#define MARGIN 1.5e-4f    // 7.5 sigma of measured logit-error rms (~2e-5)
#define BK 128            // k-elements per chunk; 4 slices of 32
#define TPB 16
#define NCHUNK (HIDDEN / BK)   // 32

using short8   = __attribute__((ext_vector_type(8))) short;   // 8 bf16 fragment
using floatx4  = __attribute__((ext_vector_type(4))) float;   // MFMA acc
using uint4v   = __attribute__((ext_vector_type(4))) unsigned int;

// d_ws: [0,4) redo cnt | [64, 64+64K) redo list |
//       [128K, 640K) W'hi packed frags | [768K, 1280K) W'lo packed frags
#define WS_LIST_OFF  (64)
#define WS_WHP_OFF   (128 * 1024)
#define WS_WLP_OFF   (768 * 1024)
#define WS_NEED      (1280 * 1024)

__device__ __forceinline__ unsigned short bf16_rn(float x) {
    unsigned int u = __builtin_bit_cast(unsigned int, x);
    unsigned int r = u + 0x7FFFu + ((u >> 16) & 1u);
    return (unsigned short)(r >> 16);
}
__device__ __forceinline__ float bf16_to_f(unsigned short h) {
    unsigned int u = ((unsigned int)h) << 16;
    return __builtin_bit_cast(float, u);
}

// ---- pass 0 (r11-proven): W -> bf16 hi/lo packed frag order ---------------
// frag (c32, et), lane l, j: e = et*16+(l&15), k = c32*32+(l>>4)*8+j.
// packed ushort offset = ((c32*4 + et)*64 + l)*8 + j.
__global__ void wconv_kernel(const float* __restrict__ W,
                             unsigned short* __restrict__ Whp,
                             unsigned short* __restrict__ Wlp,
                             int* __restrict__ cnt) {
    if (blockIdx.x == 0 && threadIdx.x == 0) *cnt = 0;
    const int id  = blockIdx.x * 256 + threadIdx.x;
    const int c32 = id >> 8;
    const int et  = (id >> 6) & 3;
    const int l   = id & 63;
    const int e   = et * 16 + (l & 15);
    const int k0  = c32 * 32 + (l >> 4) * 8;
    const float4 a = *reinterpret_cast<const float4*>(W + (size_t)e * HIDDEN + k0);
    const float4 b = *reinterpret_cast<const float4*>(W + (size_t)e * HIDDEN + k0 + 4);
    const float xs[8] = {a.x, a.y, a.z, a.w, b.x, b.y, b.z, b.w};
    short8 hv, lv;
#pragma unroll
    for (int j = 0; j < 8; ++j) {
        unsigned short h = bf16_rn(xs[j]);
        hv[j] = (short)h;
        lv[j] = (short)bf16_rn(xs[j] - bf16_to_f(h));
    }
    const size_t off = ((size_t)(c32 * 4 + et) * 64 + l) * 8;
    *reinterpret_cast<short8*>(Whp + off) = hv;
    *reinterpret_cast<short8*>(Wlp + off) = lv;
}

// ---- pass 1: MFMA gate — convert-once staging, BK=128 (r19-proven best) ---
// 256 thr = 4 waves; block = 16 tok x 64 exp; wave q = expert tile q.
// Measured sweep: (TPB,BK) = (16,256)=198, (16,128)=180 BEST, (8,128)=197,
// (8,64)=212 total us. This is the (16,128) optimum, byte-identical to r19.
__global__ __launch_bounds__(256, 4)
void gate_mfma(const float* __restrict__ X,
               const unsigned short* __restrict__ Whp,
               const unsigned short* __restrict__ Wlp,
               float* __restrict__ out_w, float* __restrict__ out_i,
               int* __restrict__ redo_cnt, int* __restrict__ redo_list, int T) {
    __shared__ __align__(16) char smem[24576];   // 3 x (4K hi + 4K lo)
    const int tid  = threadIdx.x;
    const int lane = tid & 63;
    const int q    = tid >> 6;              // 0..3 = expert tile
    const int t0   = blockIdx.x * TPB;
    const int m16  = lane & 15;             // staging k-8-group
    const int rloc = q * 4 + (lane >> 4);   // block-local token row staged

    const float* xsrc = X + (size_t)(t0 + rloc) * HIDDEN + m16 * 8;

    float4 gxa, gxb;                        // in-flight X chunk (8 floats)
#define GXLOAD(c) do {                                                            \
    const float* p_ = xsrc + (c) * BK;                                            \
    gxa = *reinterpret_cast<const float4*>(p_);                                   \
    gxb = *reinterpret_cast<const float4*>(p_ + 4);                               \
} while (0)

#define CONVWRITE(buf) do {                                                       \
    char* base_ = smem + (buf) * 8192;                                            \
    const float f_[8] = {gxa.x, gxa.y, gxa.z, gxa.w, gxb.x, gxb.y, gxb.z, gxb.w}; \
    unsigned int H_[4], L_[4];                                                    \
    _Pragma("unroll")                                                             \
    for (int p_ = 0; p_ < 4; ++p_) {                                              \
        unsigned int u0_ = __builtin_bit_cast(unsigned int, f_[2 * p_]);          \
        unsigned int u1_ = __builtin_bit_cast(unsigned int, f_[2 * p_ + 1]);      \
        H_[p_] = __builtin_amdgcn_perm(u1_, u0_, 0x07060302u);                    \
        float d0_ = f_[2 * p_]     - __builtin_bit_cast(float, u0_ & 0xFFFF0000u);\
        float d1_ = f_[2 * p_ + 1] - __builtin_bit_cast(float, u1_ & 0xFFFF0000u);\
        L_[p_] = __builtin_amdgcn_perm(__builtin_bit_cast(unsigned int, d1_),     \
                                       __builtin_bit_cast(unsigned int, d0_),     \
                                       0x07060302u);                              \
    }                                                                             \
    const int off_  = m16 * 16 + rloc;                                            \
    const int byte_ = (off_ << 4) ^ (((off_ >> 4) & 7) << 4);                     \
    uint4v hv_ = {H_[0], H_[1], H_[2], H_[3]};                                    \
    uint4v lv_ = {L_[0], L_[1], L_[2], L_[3]};                                    \
    *reinterpret_cast<uint4v*>(base_ + byte_) = hv_;                              \
    *reinterpret_cast<uint4v*>(base_ + 4096 + byte_) = lv_;                       \
} while (0)

    // packed W' base for et=q; chunk c, half h, sub s_: c32 = 4c + 2h + s_
    const unsigned short* whb = Whp + (size_t)q * 512 + (size_t)lane * 8;
    const unsigned short* wlb = Wlp + (size_t)q * 512 + (size_t)lane * 8;
#define LOADW(WH, WL, c, h) do {                                                  \
    _Pragma("unroll")                                                             \
    for (int s_ = 0; s_ < 2; ++s_) {                                              \
        WH[s_] = *reinterpret_cast<const short8*>(                                \
            whb + (size_t)(4 * (c) + 2 * (h) + s_) * 2048);                       \
        WL[s_] = *reinterpret_cast<const short8*>(                                \
            wlb + (size_t)(4 * (c) + 2 * (h) + s_) * 2048);                       \
    }                                                                             \
} while (0)

    floatx4 accA = {0.f,0.f,0.f,0.f}, accB = {0.f,0.f,0.f,0.f};

    // pure-frag compute: slice sl = 2h + s_; A-frag at off = 64*sl + lane
#define COMPUTE_HALF(buf, h, WH, WL) do {                                         \
    const char* xb_ = smem + (buf) * 8192;                                        \
    _Pragma("unroll")                                                             \
    for (int s_ = 0; s_ < 2; ++s_) {                                              \
        const int off_  = 64 * (2 * (h) + s_) + lane;                             \
        const int byte_ = (off_ << 4) ^ (((off_ >> 4) & 7) << 4);                 \
        const short8 ah_ = *reinterpret_cast<const short8*>(xb_ + byte_);         \
        const short8 al_ = *reinterpret_cast<const short8*>(xb_ + 4096 + byte_);  \
        floatx4& A_ = (s_ & 1) ? accB : accA;                                     \
        A_ = __builtin_amdgcn_mfma_f32_16x16x32_bf16(ah_, WH[s_], A_, 0, 0, 0);   \
        A_ = __builtin_amdgcn_mfma_f32_16x16x32_bf16(ah_, WL[s_], A_, 0, 0, 0);   \
        A_ = __builtin_amdgcn_mfma_f32_16x16x32_bf16(al_, WH[s_], A_, 0, 0, 0);   \
    }                                                                             \
} while (0)

    short8 whA[2], wlA[2], whB[2], wlB[2];

    // prologue: stage chunks 0 and 1, preload W(0, h0)
    GXLOAD(0); CONVWRITE(0);
    GXLOAD(1); CONVWRITE(1);
    LOADW(whA, wlA, 0, 0);
    __builtin_amdgcn_sched_barrier(0);
    asm volatile("s_waitcnt lgkmcnt(0)\n\ts_barrier" ::: "memory");
    __builtin_amdgcn_sched_barrier(0);

#pragma unroll 1
    for (int c = 0; c < NCHUNK; ++c) {
        if (c + 2 < NCHUNK) GXLOAD(c + 2);           // issue early (T14)
        LOADW(whB, wlB, c, 1);
        __builtin_amdgcn_sched_barrier(0);
        COMPUTE_HALF(c % 3, 0, whA, wlA);
        if (c + 1 < NCHUNK) LOADW(whA, wlA, c + 1, 0);
        __builtin_amdgcn_sched_barrier(0);
        COMPUTE_HALF(c % 3, 1, whB, wlB);
        if (c + 2 < NCHUNK) CONVWRITE((c + 2) % 3);  // write late, 2 ahead
        __builtin_amdgcn_sched_barrier(0);
        asm volatile("s_waitcnt lgkmcnt(0)\n\ts_barrier" ::: "memory");
        __builtin_amdgcn_sched_barrier(0);
    }
    floatx4 acc;
#pragma unroll
    for (int r = 0; r < 4; ++r) acc[r] = accA[r] + accB[r];

    __syncthreads();
    // D layout (verified r4-r21): col = lane&15 (expert), row = (lane>>4)*4+r
    float* accs = reinterpret_cast<float*>(smem);   // [16][68] overlay
    const int drow = (lane >> 4) * 4;
    const int dcol = q * 16 + (lane & 15);
#pragma unroll
    for (int r = 0; r < 4; ++r) accs[(drow + r) * 68 + dcol] = acc[r];
    __syncthreads();

    // epilogue (proven): wave q rows 4q..4q+3; lane = expert
#pragma unroll 1
    for (int m = 0; m < 4; ++m) {
        const int row = q * 4 + m;
        const int t = t0 + row;
        float lg = accs[row * 68 + lane];
        float v = 30.0f * tanhf(lg * (1.0f / 30.0f));
        float vcur = v, vmax0 = 0.f, my_e = 0.f, sum = 0.f, prev = 0.f;
        int   my_i = 0;
        bool  ambig = false;
#pragma unroll 1
        for (int k = 0; k < TOPK + 1; ++k) {   // ranks 1..9 with margin check
            float bv = vcur;
            int   bi = lane;
#pragma unroll
            for (int s = 32; s >= 1; s >>= 1) {
                float ov = __shfl_xor(bv, s);
                int   oi = __shfl_xor(bi, s);
                if (ov > bv || (ov == bv && oi < bi)) { bv = ov; bi = oi; }
            }
            if (k == 0) vmax0 = bv;
            else        ambig |= (prev - bv < MARGIN);
            prev = bv;
            if (k < TOPK) {
                float e = __expf(bv - vmax0);
                sum += e;
                if (lane == k) { my_e = e; my_i = bi; }
                if (lane == bi) vcur = -INFINITY;
            }
        }
        if (!ambig) {
            if (lane < TOPK) {
                out_w[(size_t)t * TOPK + lane] = my_e / sum;
                out_i[(size_t)t * TOPK + lane] = (float)my_i;
            }
        } else if (lane == 0) {
            redo_list[atomicAdd(redo_cnt, 1)] = t;
        }
    }
#undef GXLOAD
#undef CONVWRITE
#undef LOADW
#undef COMPUTE_HALF
}

// ---- pass 2: exact f64 redo (proven, unchanged; grid 512) -----------------
__global__ __launch_bounds__(256, 2)
void gate_redo(const float* __restrict__ X, const float* __restrict__ W,
               float* __restrict__ out,
               const int* __restrict__ redo_cnt, const int* __restrict__ redo_list,
               int T) {
    __shared__ double lgs[64];
    const int lane = threadIdx.x & 63;
    const int q    = threadIdx.x >> 6;
    const int n    = *redo_cnt;
    float* out_w = out;
    float* out_i = out + (size_t)T * TOPK;

    for (int i = blockIdx.x; i < n; i += gridDim.x) {
        const int t = redo_list[i];
        const float* xr = X + (size_t)t * HIDDEN;
#pragma unroll 1
        for (int j = 0; j < 16; ++j) {
            const int e = q * 16 + j;
            const float* wr = W + (size_t)e * HIDDEN;
            double s = 0.0;
#pragma unroll 2
            for (int k = lane * 4; k < HIDDEN; k += 256) {
                float4 wv = *reinterpret_cast<const float4*>(wr + k);
                float4 xv = *reinterpret_cast<const float4*>(xr + k);
                s = fma((double)xv.x, (double)wv.x, s);
                s = fma((double)xv.y, (double)wv.y, s);
                s = fma((double)xv.z, (double)wv.z, s);
                s = fma((double)xv.w, (double)wv.w, s);
            }
#pragma unroll
            for (int sft = 32; sft >= 1; sft >>= 1) s += __shfl_xor(s, sft);
            if (lane == 0) lgs[e] = s;
        }
        __syncthreads();
        if (q == 0) {
            double vv = 30.0 * tanh(lgs[lane] * (1.0 / 30.0));
            double dmax0 = 0.0, dmy_e = 0.0, dsum = 0.0;
            int    dmy_i = 0;
#pragma unroll 1
            for (int k = 0; k < TOPK; ++k) {
                double bv = vv;
                int    bi = lane;
#pragma unroll
                for (int s = 32; s >= 1; s >>= 1) {
                    double ov = __shfl_xor(bv, s);
                    int    oi = __shfl_xor(bi, s);
                    if (ov > bv || (ov == bv && oi < bi)) { bv = ov; bi = oi; }
                }
                if (k == 0) dmax0 = bv;
                double e = exp(bv - dmax0);
                dsum += e;
                if (lane == k) { dmy_e = e; dmy_i = bi; }
                if (lane == bi) vv = -HUGE_VAL;
            }
            if (lane < TOPK) {
                out_w[(size_t)t * TOPK + lane] = (float)(dmy_e / dsum);
                out_i[(size_t)t * TOPK + lane] = (float)dmy_i;
            }
        }
        __syncthreads();
    }
}

// ---- fallback (round-3 proven) --------------------------------------------
#define F_HC 64
#define F_LDS_STRIDE 68
#define F_TPW 4
#define F_TPB 16

__global__ __launch_bounds__(256, 4)
void moe_gate_fallback(const float* __restrict__ X, const float* __restrict__ W,
                       float* __restrict__ out, int T) {
    __shared__ float wlds[NEXP * F_LDS_STRIDE];
    const int tid  = threadIdx.x;
    const int lane = tid & 63;
    const int wid  = tid >> 6;
    const int t0   = blockIdx.x * F_TPB + wid * F_TPW;
    double accd[F_TPW];
#pragma unroll
    for (int m = 0; m < F_TPW; ++m) accd[m] = 0.0;
    for (int hb = 0; hb < HIDDEN; hb += F_HC) {
        __syncthreads();
#pragma unroll
        for (int k = 0; k < 4; ++k) {
            int f = tid + k * 256, e = f >> 4, c4 = f & 15;
            const float4 wv = *reinterpret_cast<const float4*>(W + e * HIDDEN + hb + c4 * 4);
            *reinterpret_cast<float4*>(&wlds[e * F_LDS_STRIDE + c4 * 4]) = wv;
        }
        __syncthreads();
        float accf[F_TPW];
#pragma unroll
        for (int m = 0; m < F_TPW; ++m) accf[m] = 0.f;
#pragma unroll 4
        for (int h4 = 0; h4 < F_HC / 4; ++h4) {
            const float4 wv = *reinterpret_cast<const float4*>(&wlds[lane * F_LDS_STRIDE + h4 * 4]);
#pragma unroll
            for (int m = 0; m < F_TPW; ++m) {
                const float4 xv = *reinterpret_cast<const float4*>(
                    X + (size_t)(t0 + m) * HIDDEN + hb + h4 * 4);
                accf[m] = fmaf(xv.x, wv.x, accf[m]);
                accf[m] = fmaf(xv.y, wv.y, accf[m]);
                accf[m] = fmaf(xv.z, wv.z, accf[m]);
                accf[m] = fmaf(xv.w, wv.w, accf[m]);
            }
        }
#pragma unroll
        for (int m = 0; m < F_TPW; ++m) accd[m] += (double)accf[m];
    }
    float* out_w = out;
    float* out_i = out + (size_t)T * TOPK;
#pragma unroll 1
    for (int m = 0; m < F_TPW; ++m) {
        const int t = t0 + m;
        double vv = 30.0 * tanh(accd[m] * (1.0 / 30.0));
        double dmax0 = 0.0, dmy_e = 0.0, dsum = 0.0;
        int dmy_i = 0;
#pragma unroll 1
        for (int k = 0; k < TOPK; ++k) {
            double bv = vv; int bi = lane;
#pragma unroll
            for (int s = 32; s >= 1; s >>= 1) {
                double ov = __shfl_xor(bv, s);
                int    oi = __shfl_xor(bi, s);
                if (ov > bv || (ov == bv && oi < bi)) { bv = ov; bi = oi; }
            }
            if (k == 0) dmax0 = bv;
            double e = exp(bv - dmax0);
            dsum += e;
            if (lane == k) { dmy_e = e; dmy_i = bi; }
            if (lane == bi) vv = -HUGE_VAL;
        }
        if (lane < TOPK) {
            out_w[(size_t)t * TOPK + lane] = (float)(dmy_e / dsum);
            out_i[(size_t)t * TOPK + lane] = (float)dmy_i;
        }
    }
}

extern "C" void kernel_launch(void* const* d_in, const int* in_sizes, int n_in,
                              void* d_out, int out_size, void* d_ws, size_t ws_size,
                              hipStream_t stream) {
    const float* X = (const float*)d_in[0];
    const float* W = (const float*)d_in[1];
    float* out = (float*)d_out;
    const int T = in_sizes[0] / HIDDEN;

    if (ws_size < WS_NEED) {
        hipLaunchKernelGGL(moe_gate_fallback, dim3(T / F_TPB), dim3(256), 0, stream, X, W, out, T);
        return;
    }
    char* ws = (char*)d_ws;
    int* cnt  = (int*)ws;
    int* list = (int*)(ws + WS_LIST_OFF);
    unsigned short* Whp = (unsigned short*)(ws + WS_WHP_OFF);
    unsigned short* Wlp = (unsigned short*)(ws + WS_WLP_OFF);

    hipLaunchKernelGGL(wconv_kernel, dim3(128), dim3(256), 0, stream, W, Whp, Wlp, cnt);
    hipLaunchKernelGGL(gate_mfma, dim3(T / TPB), dim3(256), 0, stream,
                       X, Whp, Wlp, out, out + (size_t)T * TOPK, cnt, list, T);
    hipLaunchKernelGGL(gate_redo, dim3(512), dim3(256), 0, stream,
                       X, W, out, cnt, list, T);
}